// Round 1
// baseline (744.148 us; speedup 1.0000x reference)
//
#include <hip/hip_runtime.h>
#include <math.h>

#define N_NODES 50000
#define N_EDGES 200000
#define N_GRAPHS 1024
#define DIM 24
#define EF 8
#define EH 128
#define DD 576   // 24*24

// ---------- helpers ----------
static __device__ __forceinline__ unsigned short f2bf(float f) {
    union { float f; unsigned int u; } v; v.f = f;
    unsigned int u = v.u;
    u += ((u >> 16) & 1u) + 0x7FFFu;   // RNE
    return (unsigned short)(u >> 16);
}
static __device__ __forceinline__ float bf2f(unsigned short s) {
    union { unsigned int u; float f; } v; v.u = ((unsigned int)s) << 16;
    return v.f;
}
static __device__ __forceinline__ float sigm(float x) { return 1.0f / (1.0f + expf(-x)); }

// ---------- deg (in-degree per node) ----------
__global__ void deg_kernel(const int* __restrict__ dst, int* __restrict__ deg) {
    int i = blockIdx.x * blockDim.x + threadIdx.x;
    if (i < N_EDGES) atomicAdd(&deg[dst[i]], 1);
}

// ---------- fused edge MLP: h = relu(ea@w1+b1); W = h@w2+b2 -> bf16 ----------
// grid (3125, 9), block 256. Tile: 64 edges x 64 cols, K = 128.
__global__ __launch_bounds__(256) void edge_mlp_kernel(
    const float* __restrict__ ea, const float* __restrict__ w1,
    const float* __restrict__ b1, const float* __restrict__ w2,
    const float* __restrict__ b2, unsigned short* __restrict__ W)
{
    __shared__ float ea_t[EF][64];     // edge_attr transposed
    __shared__ float As[EH][64];       // h transposed: As[k][e_local]
    __shared__ float Bs[64][64];       // w2 chunk [k_local][n_local]

    const int t  = threadIdx.x;
    const int e0 = blockIdx.x * 64;
    const int n0 = blockIdx.y * 64;

    // load 64x8 edge_attr tile, transposed (coalesced float4)
    if (t < 128) {
        int el = t >> 1, j = (t & 1) << 2;
        float4 v = *(const float4*)(ea + (size_t)(e0 + el) * EF + j);
        ea_t[j + 0][el] = v.x; ea_t[j + 1][el] = v.y;
        ea_t[j + 2][el] = v.z; ea_t[j + 3][el] = v.w;
    }
    __syncthreads();

    // stage A: h[k][e] = relu(b1[k] + sum_j ea[e][j]*w1[j][k])
    for (int idx = t; idx < EH * 64; idx += 256) {
        int k = idx >> 6, e = idx & 63;
        float a = b1[k];
        #pragma unroll
        for (int j = 0; j < EF; ++j) a = fmaf(ea_t[j][e], w1[j * EH + k], a);
        As[k][e] = fmaxf(a, 0.0f);
    }

    // stage B: 64x64 GEMM tile, 4x4 microtile per thread
    const int tx = t & 15, ty = t >> 4;
    float acc[4][4];
    #pragma unroll
    for (int i = 0; i < 4; ++i)
        #pragma unroll
        for (int j = 0; j < 4; ++j) acc[i][j] = 0.0f;

    for (int kk = 0; kk < EH; kk += 64) {
        __syncthreads();   // As ready (iter 0) / prev FMA done (iter 1)
        #pragma unroll
        for (int p = 0; p < 4; ++p) {
            int idx = t + p * 256;            // float4 id in 64x64 chunk
            int r = idx >> 4, c = (idx & 15) << 2;
            *(float4*)&Bs[r][c] = *(const float4*)(w2 + (size_t)(kk + r) * DD + n0 + c);
        }
        __syncthreads();
        #pragma unroll 8
        for (int k = 0; k < 64; ++k) {
            float4 av = *(const float4*)&As[kk + k][ty << 2];
            float4 bv = *(const float4*)&Bs[k][tx << 2];
            float ar[4] = {av.x, av.y, av.z, av.w};
            float br[4] = {bv.x, bv.y, bv.z, bv.w};
            #pragma unroll
            for (int i = 0; i < 4; ++i)
                #pragma unroll
                for (int j = 0; j < 4; ++j)
                    acc[i][j] = fmaf(ar[i], br[j], acc[i][j]);
        }
    }

    // epilogue: +b2, convert to bf16, 8B stores
    #pragma unroll
    for (int i = 0; i < 4; ++i) {
        int e = e0 + (ty << 2) + i;
        int n = n0 + (tx << 2);
        ushort4 s;
        s.x = f2bf(acc[i][0] + b2[n + 0]);
        s.y = f2bf(acc[i][1] + b2[n + 1]);
        s.z = f2bf(acc[i][2] + b2[n + 2]);
        s.w = f2bf(acc[i][3] + b2[n + 3]);
        *(ushort4*)(W + (size_t)e * DD + n) = s;
    }
}

// ---------- messages: msg[e][o] = sum_i x[src[e]][i] * W[e][i*24+o]; scatter to agg ----------
// block 384 = 16 edges x 24 lanes; grid 12500
__global__ __launch_bounds__(384) void msg_kernel(
    const float* __restrict__ x, const unsigned short* __restrict__ W,
    const int* __restrict__ src, const int* __restrict__ dst,
    float* __restrict__ agg)
{
    __shared__ float xs[16][24];
    __shared__ unsigned short Ws[16][DD];
    const int e0 = blockIdx.x * 16;
    const int t = threadIdx.x;

    if (t < 96) {                    // 16 rows x 6 float4
        int el = t / 6, j4 = (t % 6) * 4;
        int s = src[e0 + el];
        *(float4*)&xs[el][j4] = *(const float4*)(x + (size_t)s * DIM + j4);
    }
    for (int idx = t; idx < 16 * 72; idx += 384) {   // 16 rows x 72 uint4 (8 bf16 each)
        int el = idx / 72, c = idx % 72;
        *(uint4*)&Ws[el][c * 8] = *(const uint4*)(W + (size_t)(e0 + el) * DD + c * 8);
    }
    __syncthreads();

    int el = t / DIM, o = t % DIM;
    float m = 0.0f;
    #pragma unroll
    for (int i = 0; i < DIM; ++i)
        m = fmaf(xs[el][i], bf2f(Ws[el][i * DIM + o]), m);
    atomicAdd(&agg[(size_t)dst[e0 + el] * DIM + o], m);
}

// ---------- combine: x_out = [relu](agg/max(deg,1) + x_in@root + bias) ----------
__global__ void combine_kernel(
    const float* __restrict__ x_in, const float* __restrict__ agg,
    const int* __restrict__ deg, const float* __restrict__ root,
    const float* __restrict__ bias, float* __restrict__ x_out, int do_relu)
{
    int t = blockIdx.x * blockDim.x + threadIdx.x;
    if (t >= N_NODES * DIM) return;
    int v = t / DIM, o = t % DIM;
    int dg = deg[v];
    float d = dg > 0 ? (float)dg : 1.0f;
    float a = agg[t] / d + bias[o];
    const float* xr = x_in + (size_t)v * DIM;
    #pragma unroll
    for (int i = 0; i < DIM; ++i) a = fmaf(xr[i], root[i * DIM + o], a);
    x_out[t] = do_relu ? fmaxf(a, 0.0f) : a;
}

// ---------- Set2Set LSTM step: one thread per (graph, d) ----------
__global__ void lstm_kernel(
    const float* __restrict__ q_star, const float* __restrict__ h_in,
    const float* __restrict__ c_in, const float* __restrict__ w_ih,
    const float* __restrict__ w_hh, const float* __restrict__ b_ih,
    const float* __restrict__ b_hh, float* __restrict__ h_out,
    float* __restrict__ c_out)
{
    int t = blockIdx.x * blockDim.x + threadIdx.x;
    if (t >= N_GRAPHS * DIM) return;
    int g = t / DIM, d = t % DIM;
    const float* qs = q_star + (size_t)g * 48;
    const float* hv = h_in + (size_t)g * DIM;
    float gate[4];
    #pragma unroll
    for (int r4 = 0; r4 < 4; ++r4) {
        int r = r4 * DIM + d;
        float a = b_ih[r] + b_hh[r];
        const float* wi = w_ih + (size_t)r * 48;
        const float* wh = w_hh + (size_t)r * DIM;
        for (int j = 0; j < 48; ++j) a = fmaf(qs[j], wi[j], a);
        #pragma unroll
        for (int j = 0; j < DIM; ++j) a = fmaf(hv[j], wh[j], a);
        gate[r4] = a;
    }
    float c = sigm(gate[1]) * c_in[t] + sigm(gate[0]) * tanhf(gate[2]);
    h_out[t] = sigm(gate[3]) * tanhf(c);
    c_out[t] = c;
}

// ---------- per-graph attention + readout (batch sorted -> binary search) ----------
__global__ __launch_bounds__(64) void attn_kernel(
    const float* __restrict__ x, const int* __restrict__ batch,
    const float* __restrict__ h, float* __restrict__ q_star,
    float* __restrict__ e_buf)
{
    const int g = blockIdx.x;
    const int t = threadIdx.x;
    __shared__ int s_lo, s_hi;
    __shared__ float qs[DIM];
    if (t == 0) {
        int lo = 0, hi = N_NODES;
        while (lo < hi) { int m = (lo + hi) >> 1; if (batch[m] < g) lo = m + 1; else hi = m; }
        s_lo = lo;
        int lo2 = lo; hi = N_NODES;
        while (lo2 < hi) { int m = (lo2 + hi) >> 1; if (batch[m] <= g) lo2 = m + 1; else hi = m; }
        s_hi = lo2;
    }
    if (t < DIM) qs[t] = h[(size_t)g * DIM + t];
    __syncthreads();
    const int lo = s_lo, hi = s_hi;

    float mx = -INFINITY;
    for (int n = lo + t; n < hi; n += 64) {
        const float* xr = x + (size_t)n * DIM;
        float e = 0.0f;
        #pragma unroll
        for (int d = 0; d < DIM; ++d) e = fmaf(xr[d], qs[d], e);
        e_buf[n] = e;
        mx = fmaxf(mx, e);
    }
    #pragma unroll
    for (int off = 32; off; off >>= 1) mx = fmaxf(mx, __shfl_xor(mx, off));
    float m = (hi > lo) ? mx : 0.0f;   // ref: e_max -> 0 when not finite

    float sum = 0.0f;
    for (int n = lo + t; n < hi; n += 64) sum += expf(e_buf[n] - m);
    #pragma unroll
    for (int off = 32; off; off >>= 1) sum += __shfl_xor(sum, off);
    float denom = fmaxf(sum, 1e-16f);

    float r[DIM];
    #pragma unroll
    for (int d = 0; d < DIM; ++d) r[d] = 0.0f;
    for (int n = lo + t; n < hi; n += 64) {
        float a = expf(e_buf[n] - m) / denom;
        const float* xr = x + (size_t)n * DIM;
        #pragma unroll
        for (int d = 0; d < DIM; ++d) r[d] = fmaf(a, xr[d], r[d]);
    }
    #pragma unroll
    for (int d = 0; d < DIM; ++d) {
        #pragma unroll
        for (int off = 32; off; off >>= 1) r[d] += __shfl_xor(r[d], off);
    }
    if (t < DIM) {
        q_star[(size_t)g * 48 + t] = qs[t];       // q part
        q_star[(size_t)g * 48 + DIM + t] = r[t];  // r part
    }
}

// ---------- head: out = relu(q_star@w_fc2+b)@w_fc3+b ----------
__global__ void head_kernel(
    const float* __restrict__ q_star, const float* __restrict__ w2,
    const float* __restrict__ b2, const float* __restrict__ w3,
    const float* __restrict__ b3, float* __restrict__ out)
{
    int g = blockIdx.x * blockDim.x + threadIdx.x;
    if (g >= N_GRAPHS) return;
    const float* q = q_star + (size_t)g * 48;
    float z[8];
    #pragma unroll
    for (int k = 0; k < 8; ++k) {
        float a = b2[k];
        for (int j = 0; j < 48; ++j) a = fmaf(q[j], w2[j * 8 + k], a);
        z[k] = fmaxf(a, 0.0f);
    }
    #pragma unroll
    for (int c = 0; c < 2; ++c) {
        float a = b3[c];
        #pragma unroll
        for (int k = 0; k < 8; ++k) a = fmaf(z[k], w3[k * 2 + c], a);
        out[(size_t)g * 2 + c] = a;
    }
}

extern "C" void kernel_launch(void* const* d_in, const int* in_sizes, int n_in,
                              void* d_out, int out_size, void* d_ws, size_t ws_size,
                              hipStream_t stream) {
    const float* x      = (const float*)d_in[0];
    const float* ea     = (const float*)d_in[1];
    const float* w_e1   = (const float*)d_in[2];
    const float* b_e1   = (const float*)d_in[3];
    const float* w_e2   = (const float*)d_in[4];
    const float* b_e2   = (const float*)d_in[5];
    const float* root   = (const float*)d_in[6];
    const float* bias_c = (const float*)d_in[7];
    const float* w_ih   = (const float*)d_in[8];
    const float* w_hh   = (const float*)d_in[9];
    const float* b_ih   = (const float*)d_in[10];
    const float* b_hh   = (const float*)d_in[11];
    const float* w_fc2  = (const float*)d_in[12];
    const float* b_fc2  = (const float*)d_in[13];
    const float* w_fc3  = (const float*)d_in[14];
    const float* b_fc3  = (const float*)d_in[15];
    const int*   eidx   = (const int*)d_in[16];
    const int*   batch  = (const int*)d_in[17];
    const int* esrc = eidx;
    const int* edst = eidx + N_EDGES;
    float* out = (float*)d_out;

    // workspace layout (bytes)
    char* ws = (char*)d_ws;
    float* agg   = (float*)(ws);                  // 4,800,000
    int*   deg   = (int*)  (ws + 4800000);        //   200,000
    float* qstar = (float*)(ws + 5000000);        //   196,608
    float* h0    = (float*)(ws + 5196608);        // 4 x 98,304
    float* c0    = h0 + 24576;
    float* h1    = c0 + 24576;
    float* c1    = h1 + 24576;
    float* ebuf  = (float*)(ws + 5589824);        //   200,000
    float* x1    = (float*)(ws + 5789824);        // 4,800,000
    float* x2    = (float*)(ws + 10589824);       // 4,800,000
    unsigned short* W = (unsigned short*)(ws + 15389824);  // 230,400,000 bf16

    // zero: agg, deg, qstar, h0/c0/h1/c1
    hipMemsetAsync(ws, 0, 5589824, stream);

    deg_kernel<<<(N_EDGES + 255) / 256, 256, 0, stream>>>(edst, deg);
    edge_mlp_kernel<<<dim3(N_EDGES / 64, DD / 64), 256, 0, stream>>>(ea, w_e1, b_e1, w_e2, b_e2, W);

    // layer 1
    msg_kernel<<<N_EDGES / 16, 384, 0, stream>>>(x, W, esrc, edst, agg);
    combine_kernel<<<(N_NODES * DIM + 255) / 256, 256, 0, stream>>>(x, agg, deg, root, bias_c, x1, 1);

    // layer 2 (same edge weights W)
    hipMemsetAsync(agg, 0, 4800000, stream);
    msg_kernel<<<N_EDGES / 16, 384, 0, stream>>>(x1, W, esrc, edst, agg);
    combine_kernel<<<(N_NODES * DIM + 255) / 256, 256, 0, stream>>>(x1, agg, deg, root, bias_c, x2, 0);

    // Set2Set: 3 iterations
    float *hA = h0, *cA = c0, *hB = h1, *cB = c1;
    for (int it = 0; it < 3; ++it) {
        lstm_kernel<<<(N_GRAPHS * DIM + 255) / 256, 256, 0, stream>>>(
            qstar, hA, cA, w_ih, w_hh, b_ih, b_hh, hB, cB);
        attn_kernel<<<N_GRAPHS, 64, 0, stream>>>(x2, batch, hB, qstar, ebuf);
        float* th = hA; hA = hB; hB = th;
        float* tc = cA; cA = cB; cB = tc;
    }

    head_kernel<<<(N_GRAPHS + 255) / 256, 256, 0, stream>>>(qstar, w_fc2, b_fc2, w_fc3, b_fc3, out);
}

// Round 2
// 450.050 us; speedup vs baseline: 1.6535x; 1.6535x over previous
//
#include <hip/hip_runtime.h>
#include <math.h>

#define N_NODES 50000
#define N_EDGES 200000
#define N_GRAPHS 1024
#define DIM 24
#define EF 8
#define EH 128
#define DD 576   // 24*24
#define SA 136   // LDS stride (bf16 elems) for A tile: 128 + 8 pad -> 2-way bank alias (free)

typedef __attribute__((ext_vector_type(8))) short short8;
typedef __attribute__((ext_vector_type(4))) float float4e;

// ---------- helpers ----------
static __device__ __forceinline__ unsigned short f2bf(float f) {
    union { float f; unsigned int u; } v; v.f = f;
    unsigned int u = v.u;
    u += ((u >> 16) & 1u) + 0x7FFFu;   // RNE
    return (unsigned short)(u >> 16);
}
static __device__ __forceinline__ float bf2f(unsigned short s) {
    union { unsigned int u; float f; } v; v.u = ((unsigned int)s) << 16;
    return v.f;
}
static __device__ __forceinline__ float sigm(float x) { return 1.0f / (1.0f + expf(-x)); }

// ---------- deg (in-degree per node) ----------
__global__ void deg_kernel(const int* __restrict__ dst, int* __restrict__ deg) {
    int i = blockIdx.x * blockDim.x + threadIdx.x;
    if (i < N_EDGES) atomicAdd(&deg[dst[i]], 1);
}

// ---------- w2 transpose + bf16: w2t[n][k] = bf16(w2[k][n]) ----------
__global__ __launch_bounds__(256) void w2t_kernel(const float* __restrict__ w2,
                                                  unsigned short* __restrict__ w2t) {
    int idx = blockIdx.x * 256 + threadIdx.x;   // idx = n*128 + k
    if (idx >= DD * EH) return;
    int n = idx >> 7, k = idx & 127;
    w2t[idx] = f2bf(w2[(size_t)k * DD + n]);
}

// ---------- fused edge MLP via MFMA ----------
// grid (2, 3125), block 256 (4 waves). Per block: 64 edges x 288 cols, K=128.
// Stage A: h = relu(ea@w1+b1) -> LDS bf16 [64][SA].
// Stage B: 16x16x32 bf16 MFMA; A-frags from LDS, B-frags direct from w2t (L2-hot).
// Wave: 2 m-tiles x 9 n-tiles -> acc 72 VGPRs.
__global__ __launch_bounds__(256) void gemm_w_kernel(
    const float* __restrict__ ea, const float* __restrict__ w1,
    const float* __restrict__ b1, const unsigned short* __restrict__ w2t,
    const float* __restrict__ b2, unsigned short* __restrict__ W)
{
    __shared__ unsigned short As[64 * SA];

    const int t  = threadIdx.x;
    const int e0 = blockIdx.y * 64;
    const int n0 = blockIdx.x * 288;

    // ---- stage A: 64 edges x 128 hid; thread = (k-slice of 4) x (8 edges) ----
    {
        const int ks = t & 31;          // k = ks*4 .. ks*4+3
        const int eb = (t >> 5) * 8;    // 8 edges starting here
        float wv[EF][4];
        #pragma unroll
        for (int j = 0; j < EF; ++j) {
            float4 v = *(const float4*)(w1 + j * EH + ks * 4);
            wv[j][0] = v.x; wv[j][1] = v.y; wv[j][2] = v.z; wv[j][3] = v.w;
        }
        float4 bv = *(const float4*)(b1 + ks * 4);
        const float bvv[4] = {bv.x, bv.y, bv.z, bv.w};
        #pragma unroll
        for (int e = 0; e < 8; ++e) {
            const float* ear = ea + (size_t)(e0 + eb + e) * EF;
            float4 a0 = *(const float4*)ear;
            float4 a1 = *(const float4*)(ear + 4);
            const float av[EF] = {a0.x, a0.y, a0.z, a0.w, a1.x, a1.y, a1.z, a1.w};
            float r[4] = {bvv[0], bvv[1], bvv[2], bvv[3]};
            #pragma unroll
            for (int j = 0; j < EF; ++j)
                #pragma unroll
                for (int c = 0; c < 4; ++c)
                    r[c] = fmaf(av[j], wv[j][c], r[c]);
            ushort4 hq;
            hq.x = f2bf(fmaxf(r[0], 0.0f));
            hq.y = f2bf(fmaxf(r[1], 0.0f));
            hq.z = f2bf(fmaxf(r[2], 0.0f));
            hq.w = f2bf(fmaxf(r[3], 0.0f));
            *(ushort4*)&As[(eb + e) * SA + ks * 4] = hq;
        }
    }
    __syncthreads();

    // ---- stage B ----
    const int lane = t & 63;
    const int wave = t >> 6;
    const int l16  = lane & 15;          // A row (m) / B col (n) / C col
    const int quad = lane >> 4;          // k sub-block / C row group
    const int mw   = (wave & 1) * 2;     // m-tile pair: tiles mw, mw+1
    const int ng   = (wave >> 1) * 9;    // n-tile group (9 tiles of 16)

    float4e acc[2][9];
    #pragma unroll
    for (int j = 0; j < 9; ++j) {
        float bb = b2[n0 + (ng + j) * 16 + l16];
        float4e v = {bb, bb, bb, bb};
        acc[0][j] = v; acc[1][j] = v;
    }

    const unsigned short* Bb = w2t + (size_t)(n0 + ng * 16 + l16) * EH + quad * 8;
    const unsigned short* A0 = As + (mw * 16 + l16) * SA + quad * 8;

    #pragma unroll
    for (int ks = 0; ks < 4; ++ks) {
        short8 a0 = *(const short8*)(A0 + ks * 32);
        short8 a1 = *(const short8*)(A0 + 16 * SA + ks * 32);
        #pragma unroll
        for (int j = 0; j < 9; ++j) {
            short8 b = *(const short8*)(Bb + (size_t)j * 16 * EH + ks * 32);
            acc[0][j] = __builtin_amdgcn_mfma_f32_16x16x32_bf16(a0, b, acc[0][j], 0, 0, 0);
            acc[1][j] = __builtin_amdgcn_mfma_f32_16x16x32_bf16(a1, b, acc[1][j], 0, 0, 0);
        }
    }

    // ---- epilogue: C row = quad*4+reg, col = l16; scalar bf16 stores (L2 merges) ----
    #pragma unroll
    for (int mm = 0; mm < 2; ++mm) {
        #pragma unroll
        for (int j = 0; j < 9; ++j) {
            int col = n0 + (ng + j) * 16 + l16;
            #pragma unroll
            for (int r = 0; r < 4; ++r) {
                int e = e0 + (mw + mm) * 16 + quad * 4 + r;
                W[(size_t)e * DD + col] = f2bf(acc[mm][j][r]);
            }
        }
    }
}

// ---------- messages: msg[e][o] = sum_i x[src[e]][i] * W[e][i*24+o]; scatter to agg ----------
// block 384 = 16 edges x 24 lanes; grid 12500
__global__ __launch_bounds__(384) void msg_kernel(
    const float* __restrict__ x, const unsigned short* __restrict__ W,
    const int* __restrict__ src, const int* __restrict__ dst,
    float* __restrict__ agg)
{
    __shared__ float xs[16][24];
    __shared__ unsigned short Ws[16][DD];
    const int e0 = blockIdx.x * 16;
    const int t = threadIdx.x;

    if (t < 96) {                    // 16 rows x 6 float4
        int el = t / 6, j4 = (t % 6) * 4;
        int s = src[e0 + el];
        *(float4*)&xs[el][j4] = *(const float4*)(x + (size_t)s * DIM + j4);
    }
    for (int idx = t; idx < 16 * 72; idx += 384) {   // 16 rows x 72 uint4 (8 bf16 each)
        int el = idx / 72, c = idx % 72;
        *(uint4*)&Ws[el][c * 8] = *(const uint4*)(W + (size_t)(e0 + el) * DD + c * 8);
    }
    __syncthreads();

    int el = t / DIM, o = t % DIM;
    float m = 0.0f;
    #pragma unroll
    for (int i = 0; i < DIM; ++i)
        m = fmaf(xs[el][i], bf2f(Ws[el][i * DIM + o]), m);
    atomicAdd(&agg[(size_t)dst[e0 + el] * DIM + o], m);
}

// ---------- combine: x_out = [relu](agg/max(deg,1) + x_in@root + bias) ----------
__global__ void combine_kernel(
    const float* __restrict__ x_in, const float* __restrict__ agg,
    const int* __restrict__ deg, const float* __restrict__ root,
    const float* __restrict__ bias, float* __restrict__ x_out, int do_relu)
{
    int t = blockIdx.x * blockDim.x + threadIdx.x;
    if (t >= N_NODES * DIM) return;
    int v = t / DIM, o = t % DIM;
    int dg = deg[v];
    float d = dg > 0 ? (float)dg : 1.0f;
    float a = agg[t] / d + bias[o];
    const float* xr = x_in + (size_t)v * DIM;
    #pragma unroll
    for (int i = 0; i < DIM; ++i) a = fmaf(xr[i], root[i * DIM + o], a);
    x_out[t] = do_relu ? fmaxf(a, 0.0f) : a;
}

// ---------- Set2Set LSTM step: one thread per (graph, d) ----------
__global__ void lstm_kernel(
    const float* __restrict__ q_star, const float* __restrict__ h_in,
    const float* __restrict__ c_in, const float* __restrict__ w_ih,
    const float* __restrict__ w_hh, const float* __restrict__ b_ih,
    const float* __restrict__ b_hh, float* __restrict__ h_out,
    float* __restrict__ c_out)
{
    int t = blockIdx.x * blockDim.x + threadIdx.x;
    if (t >= N_GRAPHS * DIM) return;
    int g = t / DIM, d = t % DIM;
    const float* qs = q_star + (size_t)g * 48;
    const float* hv = h_in + (size_t)g * DIM;
    float gate[4];
    #pragma unroll
    for (int r4 = 0; r4 < 4; ++r4) {
        int r = r4 * DIM + d;
        float a = b_ih[r] + b_hh[r];
        const float* wi = w_ih + (size_t)r * 48;
        const float* wh = w_hh + (size_t)r * DIM;
        for (int j = 0; j < 48; ++j) a = fmaf(qs[j], wi[j], a);
        #pragma unroll
        for (int j = 0; j < DIM; ++j) a = fmaf(hv[j], wh[j], a);
        gate[r4] = a;
    }
    float c = sigm(gate[1]) * c_in[t] + sigm(gate[0]) * tanhf(gate[2]);
    h_out[t] = sigm(gate[3]) * tanhf(c);
    c_out[t] = c;
}

// ---------- per-graph attention + readout (batch sorted -> binary search) ----------
__global__ __launch_bounds__(64) void attn_kernel(
    const float* __restrict__ x, const int* __restrict__ batch,
    const float* __restrict__ h, float* __restrict__ q_star,
    float* __restrict__ e_buf)
{
    const int g = blockIdx.x;
    const int t = threadIdx.x;
    __shared__ int s_lo, s_hi;
    __shared__ float qs[DIM];
    if (t == 0) {
        int lo = 0, hi = N_NODES;
        while (lo < hi) { int m = (lo + hi) >> 1; if (batch[m] < g) lo = m + 1; else hi = m; }
        s_lo = lo;
        int lo2 = lo; hi = N_NODES;
        while (lo2 < hi) { int m = (lo2 + hi) >> 1; if (batch[m] <= g) lo2 = m + 1; else hi = m; }
        s_hi = lo2;
    }
    if (t < DIM) qs[t] = h[(size_t)g * DIM + t];
    __syncthreads();
    const int lo = s_lo, hi = s_hi;

    float mx = -INFINITY;
    for (int n = lo + t; n < hi; n += 64) {
        const float* xr = x + (size_t)n * DIM;
        float e = 0.0f;
        #pragma unroll
        for (int d = 0; d < DIM; ++d) e = fmaf(xr[d], qs[d], e);
        e_buf[n] = e;
        mx = fmaxf(mx, e);
    }
    #pragma unroll
    for (int off = 32; off; off >>= 1) mx = fmaxf(mx, __shfl_xor(mx, off));
    float m = (hi > lo) ? mx : 0.0f;   // ref: e_max -> 0 when not finite

    float sum = 0.0f;
    for (int n = lo + t; n < hi; n += 64) sum += expf(e_buf[n] - m);
    #pragma unroll
    for (int off = 32; off; off >>= 1) sum += __shfl_xor(sum, off);
    float denom = fmaxf(sum, 1e-16f);

    float r[DIM];
    #pragma unroll
    for (int d = 0; d < DIM; ++d) r[d] = 0.0f;
    for (int n = lo + t; n < hi; n += 64) {
        float a = expf(e_buf[n] - m) / denom;
        const float* xr = x + (size_t)n * DIM;
        #pragma unroll
        for (int d = 0; d < DIM; ++d) r[d] = fmaf(a, xr[d], r[d]);
    }
    #pragma unroll
    for (int d = 0; d < DIM; ++d) {
        #pragma unroll
        for (int off = 32; off; off >>= 1) r[d] += __shfl_xor(r[d], off);
    }
    if (t < DIM) {
        q_star[(size_t)g * 48 + t] = qs[t];       // q part
        q_star[(size_t)g * 48 + DIM + t] = r[t];  // r part
    }
}

// ---------- head: out = relu(q_star@w_fc2+b)@w_fc3+b ----------
__global__ void head_kernel(
    const float* __restrict__ q_star, const float* __restrict__ w2,
    const float* __restrict__ b2, const float* __restrict__ w3,
    const float* __restrict__ b3, float* __restrict__ out)
{
    int g = blockIdx.x * blockDim.x + threadIdx.x;
    if (g >= N_GRAPHS) return;
    const float* q = q_star + (size_t)g * 48;
    float z[8];
    #pragma unroll
    for (int k = 0; k < 8; ++k) {
        float a = b2[k];
        for (int j = 0; j < 48; ++j) a = fmaf(q[j], w2[j * 8 + k], a);
        z[k] = fmaxf(a, 0.0f);
    }
    #pragma unroll
    for (int c = 0; c < 2; ++c) {
        float a = b3[c];
        #pragma unroll
        for (int k = 0; k < 8; ++k) a = fmaf(z[k], w3[k * 2 + c], a);
        out[(size_t)g * 2 + c] = a;
    }
}

extern "C" void kernel_launch(void* const* d_in, const int* in_sizes, int n_in,
                              void* d_out, int out_size, void* d_ws, size_t ws_size,
                              hipStream_t stream) {
    const float* x      = (const float*)d_in[0];
    const float* ea     = (const float*)d_in[1];
    const float* w_e1   = (const float*)d_in[2];
    const float* b_e1   = (const float*)d_in[3];
    const float* w_e2   = (const float*)d_in[4];
    const float* b_e2   = (const float*)d_in[5];
    const float* root   = (const float*)d_in[6];
    const float* bias_c = (const float*)d_in[7];
    const float* w_ih   = (const float*)d_in[8];
    const float* w_hh   = (const float*)d_in[9];
    const float* b_ih   = (const float*)d_in[10];
    const float* b_hh   = (const float*)d_in[11];
    const float* w_fc2  = (const float*)d_in[12];
    const float* b_fc2  = (const float*)d_in[13];
    const float* w_fc3  = (const float*)d_in[14];
    const float* b_fc3  = (const float*)d_in[15];
    const int*   eidx   = (const int*)d_in[16];
    const int*   batch  = (const int*)d_in[17];
    const int* esrc = eidx;
    const int* edst = eidx + N_EDGES;
    float* out = (float*)d_out;

    // workspace layout (bytes)
    char* ws = (char*)d_ws;
    float* agg   = (float*)(ws);                  // 4,800,000
    int*   deg   = (int*)  (ws + 4800000);        //   200,000
    float* qstar = (float*)(ws + 5000000);        //   196,608
    float* h0    = (float*)(ws + 5196608);        // 4 x 98,304
    float* c0    = h0 + 24576;
    float* h1    = c0 + 24576;
    float* c1    = h1 + 24576;
    float* ebuf  = (float*)(ws + 5589824);        //   200,000
    float* x1    = (float*)(ws + 5789824);        // 4,800,000
    float* x2    = (float*)(ws + 10589824);       // 4,800,000
    unsigned short* W   = (unsigned short*)(ws + 15389824);   // 230,400,000 bf16
    unsigned short* w2t = (unsigned short*)(ws + 245789824);  // 147,456 bf16

    // zero: agg, deg, qstar, h0/c0/h1/c1
    hipMemsetAsync(ws, 0, 5589824, stream);

    deg_kernel<<<(N_EDGES + 255) / 256, 256, 0, stream>>>(edst, deg);
    w2t_kernel<<<(DD * EH + 255) / 256, 256, 0, stream>>>(w_e2, w2t);
    gemm_w_kernel<<<dim3(2, N_EDGES / 64), 256, 0, stream>>>(ea, w_e1, b_e1, w2t, b_e2, W);

    // layer 1
    msg_kernel<<<N_EDGES / 16, 384, 0, stream>>>(x, W, esrc, edst, agg);
    combine_kernel<<<(N_NODES * DIM + 255) / 256, 256, 0, stream>>>(x, agg, deg, root, bias_c, x1, 1);

    // layer 2 (same edge weights W)
    hipMemsetAsync(agg, 0, 4800000, stream);
    msg_kernel<<<N_EDGES / 16, 384, 0, stream>>>(x1, W, esrc, edst, agg);
    combine_kernel<<<(N_NODES * DIM + 255) / 256, 256, 0, stream>>>(x1, agg, deg, root, bias_c, x2, 0);

    // Set2Set: 3 iterations
    float *hA = h0, *cA = c0, *hB = h1, *cB = c1;
    for (int it = 0; it < 3; ++it) {
        lstm_kernel<<<(N_GRAPHS * DIM + 255) / 256, 256, 0, stream>>>(
            qstar, hA, cA, w_ih, w_hh, b_ih, b_hh, hB, cB);
        attn_kernel<<<N_GRAPHS, 64, 0, stream>>>(x2, batch, hB, qstar, ebuf);
        float* th = hA; hA = hB; hB = th;
        float* tc = cA; cA = cB; cB = tc;
    }

    head_kernel<<<(N_GRAPHS + 255) / 256, 256, 0, stream>>>(qstar, w_fc2, b_fc2, w_fc3, b_fc3, out);
}